// Round 9
// baseline (226.260 us; speedup 1.0000x reference)
//
#include <hip/hip_runtime.h>

#define H 128
#define NREG 8
#define KE 8
#define TILE (256 * KE)    // k_bin: 2048 edges/block
#define SCAP 3072          // per-sub-bucket csr slot capacity (avg 2048)
#define RCAP 220160        // per-region capacity (avg 200000, +10% headroom)

typedef __attribute__((ext_vector_type(8))) short short8_t;   // 8 bf16
typedef __attribute__((ext_vector_type(4))) float float4_t;

__device__ __forceinline__ ushort f2bf(float f) {
  uint u = __float_as_uint(f);
  u += 0x7fff + ((u >> 16) & 1);          // RNE
  return (ushort)(u >> 16);
}
__device__ __forceinline__ float bflo(uint v) { return __uint_as_float(v << 16); }
__device__ __forceinline__ float bfhi(uint v) { return __uint_as_float(v & 0xffff0000u); }

// ---------- phase A: bin edges into 8 dst-regions, packed (src<<14 | d_local) ----------
// LDS-staged so global writes are 8 dense runs (~1 KB each) per block.
__global__ __launch_bounds__(256) void k_bin(const int* __restrict__ src, const int* __restrict__ dst,
                                             int* gcur, int* __restrict__ breg, int E, int npr) {
  __shared__ int cnt8[NREG], gbase8[NREG], lpre8[NREG + 1];
  __shared__ int staged[TILE];
  const int tid = threadIdx.x;
  if (tid < NREG) cnt8[tid] = 0;
  __syncthreads();
  const int base = blockIdx.x * TILE;
  int pk[KE], r[KE], off[KE];
  #pragma unroll
  for (int k = 0; k < KE; ++k) {
    const int e = base + k * 256 + tid;
    if (e < E) {
      const int s = src[e], d = dst[e];
      r[k] = (int)((unsigned)d / (unsigned)npr);
      pk[k] = (s << 14) | (d - r[k] * npr);
      off[k] = atomicAdd(&cnt8[r[k]], 1);
    } else r[k] = -1;
  }
  __syncthreads();
  if (tid == 0) {
    int acc = 0;
    #pragma unroll
    for (int j = 0; j < NREG; ++j) { lpre8[j] = acc; acc += cnt8[j]; }
    lpre8[NREG] = acc;
  }
  if (tid < NREG) gbase8[tid] = atomicAdd(&gcur[tid], cnt8[tid]);
  __syncthreads();
  #pragma unroll
  for (int k = 0; k < KE; ++k)
    if (r[k] >= 0) staged[lpre8[r[k]] + off[k]] = pk[k];
  __syncthreads();
  const int tot = lpre8[NREG];
  for (int i = tid; i < tot; i += 256) {
    int reg = 0;
    #pragma unroll
    for (int j = 1; j < NREG; ++j) reg += (i >= lpre8[j]);
    const int p = gbase8[reg] + (i - lpre8[reg]);
    if (p < RCAP) breg[reg * RCAP + p] = staged[i];
  }
}

// ---------- phase B: one block per 128-node sub-bucket ----------
// Streams its region bucket (XCD-local L2), filters its nodes (~1% match),
// LDS count -> scan -> counting sort; writes dinv, rowinfo=(off,cnt), dense csr.
__global__ __launch_bounds__(256) void k_sort(const int* __restrict__ breg, const int* __restrict__ gcur,
                                              float* __restrict__ dinv, uint2* __restrict__ rowinfo,
                                              int* __restrict__ csr, int N, int npr) {
  __shared__ int cnt[128], pre[128], lcur[128];
  __shared__ int stage[SCAP], sorted[SCAP];
  __shared__ int sc;
  const int tid = threadIdx.x;
  const int r = blockIdx.x & 7;
  const int sub = blockIdx.x >> 3;
  if (tid < 128) { cnt[tid] = 0; }
  if (tid == 0) sc = 0;
  __syncthreads();

  const int T = min(gcur[r], RCAP);
  const int* bp = breg + (size_t)r * RCAP;
  const int4* bp4 = (const int4*)bp;
  const int subkey = sub << 7;

  #define PROC(v)                                                     \
    if (((v) & 0x3F80) == subkey) {                                   \
      const int p_ = atomicAdd(&sc, 1);                               \
      if (p_ < SCAP) {                                                \
        stage[p_] = ((int)((unsigned)(v) >> 14) << 7) | ((v) & 127);  \
        atomicAdd(&cnt[(v) & 127], 1);                                \
      }                                                               \
    }

  const int nq = T >> 2;
  for (int i4 = tid; i4 < nq; i4 += 256) {
    const int4 q = bp4[i4];
    PROC(q.x) PROC(q.y) PROC(q.z) PROC(q.w)
  }
  if (tid < (T & 3)) { const int v = bp[(nq << 2) + tid]; PROC(v) }
  #undef PROC
  __syncthreads();

  // exclusive scan of cnt[128]
  if (tid < 128) pre[tid] = cnt[tid];
  __syncthreads();
  for (int off = 1; off < 128; off <<= 1) {
    int v = 0;
    if (tid < 128 && tid >= off) v = pre[tid - off];
    __syncthreads();
    if (tid < 128) pre[tid] += v;
    __syncthreads();
  }
  if (tid < 128) pre[tid] -= cnt[tid];
  __syncthreads();

  // per-node outputs
  int nodes = npr - sub * 128; if (nodes > 128) nodes = 128;
  const int gn0 = r * npr + sub * 128;
  if (N - gn0 < nodes) nodes = N - gn0;
  const int slot = blockIdx.x * SCAP;
  if (tid < nodes) {
    const int c = cnt[tid];
    dinv[gn0 + tid] = rsqrtf((float)(1 + c));
    rowinfo[gn0 + tid] = make_uint2((uint)(slot + pre[tid]), (uint)c);
    lcur[tid] = pre[tid];
  }
  __syncthreads();

  // counting sort stage -> sorted
  const int scc = min(sc, SCAP);
  for (int i = tid; i < scc; i += 256) {
    const int v = stage[i];
    const int p = atomicAdd(&lcur[v & 127], 1);
    sorted[p] = (int)((unsigned)v >> 7);
  }
  __syncthreads();
  for (int i = tid; i < scc; i += 256) csr[slot + i] = sorted[i];
}

// ---------- linear: hs = (x @ W^T) * dinv[row], bf16 ----------
__global__ __launch_bounds__(256) void k_linear(const float* __restrict__ x, const float* __restrict__ W,
                                                const float* __restrict__ dinv, ushort* __restrict__ hs, int N) {
  __shared__ float CT[32 * 128];
  const int tid  = threadIdx.x;
  const int lane = tid & 63;
  const int wid  = tid >> 6;
  const int rg   = wid >> 1;
  const int cg   = wid & 1;
  const int q    = lane >> 4;
  const int lm   = lane & 15;

  short8_t bfr[4][4];
  #pragma unroll
  for (int kk = 0; kk < 4; ++kk) {
    #pragma unroll
    for (int nf = 0; nf < 4; ++nf) {
      const float* wp = W + (cg * 64 + nf * 16 + lm) * 128 + kk * 32 + q * 8;
      float4_t w0 = *(const float4_t*)wp;
      float4_t w1 = *(const float4_t*)(wp + 4);
      union { short8_t s; ushort u[8]; } t;
      t.u[0] = f2bf(w0.x); t.u[1] = f2bf(w0.y); t.u[2] = f2bf(w0.z); t.u[3] = f2bf(w0.w);
      t.u[4] = f2bf(w1.x); t.u[5] = f2bf(w1.y); t.u[6] = f2bf(w1.z); t.u[7] = f2bf(w1.w);
      bfr[kk][nf] = t.s;
    }
  }

  const int ntiles = (N + 31) / 32;
  for (int tile = blockIdx.x; tile < ntiles; tile += gridDim.x) {
    const int n0 = tile * 32;
    const int arow = n0 + rg * 16 + lm;
    const int arow_c = (arow < N) ? arow : (N - 1);
    const float* xp = x + (long)arow_c * H + q * 8;
    short8_t afr[4];
    #pragma unroll
    for (int kk = 0; kk < 4; ++kk) {
      float4_t x0 = *(const float4_t*)(xp + kk * 32);
      float4_t x1 = *(const float4_t*)(xp + kk * 32 + 4);
      union { short8_t s; ushort u[8]; } t;
      t.u[0] = f2bf(x0.x); t.u[1] = f2bf(x0.y); t.u[2] = f2bf(x0.z); t.u[3] = f2bf(x0.w);
      t.u[4] = f2bf(x1.x); t.u[5] = f2bf(x1.y); t.u[6] = f2bf(x1.z); t.u[7] = f2bf(x1.w);
      afr[kk] = t.s;
    }

    float4_t acc[4];
    #pragma unroll
    for (int nf = 0; nf < 4; ++nf) acc[nf] = (float4_t){0.f, 0.f, 0.f, 0.f};
    #pragma unroll
    for (int kk = 0; kk < 4; ++kk) {
      #pragma unroll
      for (int nf = 0; nf < 4; ++nf)
        acc[nf] = __builtin_amdgcn_mfma_f32_16x16x32_bf16(afr[kk], bfr[kk][nf], acc[nf], 0, 0, 0);
    }

    #pragma unroll
    for (int nf = 0; nf < 4; ++nf) {
      #pragma unroll
      for (int rr = 0; rr < 4; ++rr)
        CT[(rg * 16 + q * 4 + rr) * 128 + cg * 64 + nf * 16 + lm] = acc[nf][rr];
    }
    __syncthreads();

    #pragma unroll
    for (int c = 0; c < 4; ++c) {
      const int flat = c * 1024 + tid * 4;
      const int row = flat >> 7;
      const int col = flat & 127;
      const int grow = n0 + row;
      if (grow < N) {
        float4_t v = *(const float4_t*)&CT[flat];
        const float dv = dinv[grow];
        uint2 pk;
        pk.x = (uint)f2bf(v.x * dv) | ((uint)f2bf(v.y * dv) << 16);
        pk.y = (uint)f2bf(v.z * dv) | ((uint)f2bf(v.w * dv) << 16);
        *(uint2*)(hs + (long)grow * H + col) = pk;
      }
    }
    __syncthreads();
  }
}

// ---------- aggregation: wave/node, 16-message rounds (4x uint4 in flight) ----------
__global__ __launch_bounds__(256) void k_agg(const ushort* __restrict__ hs, const float* __restrict__ dinv,
                                             const uint2* __restrict__ rowinfo, const int* __restrict__ csr,
                                             const float* __restrict__ bias, float* __restrict__ out, int N) {
  const int d = blockIdx.x * 4 + (threadIdx.x >> 6);
  if (d >= N) return;
  const int l = threadIdx.x & 63;
  const int g = l >> 4, j = l & 15;
  const uint4* hp = (const uint4*)hs;          // 16 uint4 per 128-bf16 row

  float a0 = 0, a1 = 0, a2 = 0, a3 = 0, a4 = 0, a5 = 0, a6 = 0, a7 = 0;
  if (g == 0) {                                // self message (hs already * dinv[d])
    const uint4 q = hp[(size_t)d * 16 + j];
    a0 = bflo(q.x); a1 = bfhi(q.x); a2 = bflo(q.y); a3 = bfhi(q.y);
    a4 = bflo(q.z); a5 = bfhi(q.z); a6 = bflo(q.w); a7 = bfhi(q.w);
  }

  const uint2 info = rowinfo[d];
  int i = (int)info.x;
  int cnt = (int)info.y;

  for (; cnt >= 16; cnt -= 16, i += 16) {
    const int sA = csr[i + g], sB = csr[i + 4 + g], sC = csr[i + 8 + g], sD = csr[i + 12 + g];
    const uint4 qA = hp[(size_t)sA * 16 + j];
    const uint4 qB = hp[(size_t)sB * 16 + j];
    const uint4 qC = hp[(size_t)sC * 16 + j];
    const uint4 qD = hp[(size_t)sD * 16 + j];
    a0 += bflo(qA.x) + bflo(qB.x) + bflo(qC.x) + bflo(qD.x);
    a1 += bfhi(qA.x) + bfhi(qB.x) + bfhi(qC.x) + bfhi(qD.x);
    a2 += bflo(qA.y) + bflo(qB.y) + bflo(qC.y) + bflo(qD.y);
    a3 += bfhi(qA.y) + bfhi(qB.y) + bfhi(qC.y) + bfhi(qD.y);
    a4 += bflo(qA.z) + bflo(qB.z) + bflo(qC.z) + bflo(qD.z);
    a5 += bfhi(qA.z) + bfhi(qB.z) + bfhi(qC.z) + bfhi(qD.z);
    a6 += bflo(qA.w) + bflo(qB.w) + bflo(qC.w) + bflo(qD.w);
    a7 += bfhi(qA.w) + bfhi(qB.w) + bfhi(qC.w) + bfhi(qD.w);
  }
  for (; cnt >= 4; cnt -= 4, i += 4) {
    const int s = csr[i + g];
    const uint4 q = hp[(size_t)s * 16 + j];
    a0 += bflo(q.x); a1 += bfhi(q.x); a2 += bflo(q.y); a3 += bfhi(q.y);
    a4 += bflo(q.z); a5 += bfhi(q.z); a6 += bflo(q.w); a7 += bfhi(q.w);
  }
  if (g < cnt) {
    const int s = csr[i + g];
    const uint4 q = hp[(size_t)s * 16 + j];
    a0 += bflo(q.x); a1 += bfhi(q.x); a2 += bflo(q.y); a3 += bfhi(q.y);
    a4 += bflo(q.z); a5 += bfhi(q.z); a6 += bflo(q.w); a7 += bfhi(q.w);
  }

  a0 += __shfl_xor(a0, 16); a1 += __shfl_xor(a1, 16);
  a2 += __shfl_xor(a2, 16); a3 += __shfl_xor(a3, 16);
  a4 += __shfl_xor(a4, 16); a5 += __shfl_xor(a5, 16);
  a6 += __shfl_xor(a6, 16); a7 += __shfl_xor(a7, 16);
  a0 += __shfl_xor(a0, 32); a1 += __shfl_xor(a1, 32);
  a2 += __shfl_xor(a2, 32); a3 += __shfl_xor(a3, 32);
  a4 += __shfl_xor(a4, 32); a5 += __shfl_xor(a5, 32);
  a6 += __shfl_xor(a6, 32); a7 += __shfl_xor(a7, 32);

  if (l < 16) {
    const float dd = dinv[d];
    const float4_t b0 = *(const float4_t*)(bias + j * 8);
    const float4_t b1 = *(const float4_t*)(bias + j * 8 + 4);
    float4_t o0, o1;
    o0.x = a0 * dd + b0.x; o0.y = a1 * dd + b0.y; o0.z = a2 * dd + b0.z; o0.w = a3 * dd + b0.w;
    o1.x = a4 * dd + b1.x; o1.y = a5 * dd + b1.y; o1.z = a6 * dd + b1.z; o1.w = a7 * dd + b1.w;
    __builtin_nontemporal_store(o0, (float4_t*)(out + (size_t)d * H + j * 8));
    __builtin_nontemporal_store(o1, (float4_t*)(out + (size_t)d * H + j * 8 + 4));
  }
}

extern "C" void kernel_launch(void* const* d_in, const int* in_sizes, int n_in,
                              void* d_out, int out_size, void* d_ws, size_t ws_size,
                              hipStream_t stream) {
  const float* x = (const float*)d_in[0];
  const int*   edge = (const int*)d_in[1];
  const float* W = (const float*)d_in[2];
  const float* b = (const float*)d_in[3];
  float* out = (float*)d_out;

  const int N = in_sizes[0] / H;     // 100000
  const int E = in_sizes[1] / 2;     // 1600000
  const int* src = edge;
  const int* dst = edge + E;
  const int npr  = (N + NREG - 1) / NREG;           // 12500
  const int nsub = (npr + 127) / 128;               // 98
  const int nsubt = NREG * nsub;                    // 784

  // workspace layout
  char* w = (char*)d_ws;
  ushort* hs     = (ushort*)w;  w += (size_t)N * H * 2;              // 25.6 MB
  float*  dinv   = (float*)w;   w += (size_t)N * 4;
  int*    gcur   = (int*)w;     w += (size_t)NREG * 4;
  uint2*  rowinfo= (uint2*)w;   w += (size_t)N * 8;                  // 800 KB
  int*    csr    = (int*)w;     w += (size_t)nsubt * SCAP * 4;       // 9.6 MB (padded slots)
  int*    breg   = (int*)w;     w += (size_t)NREG * RCAP * 4;        // 7.0 MB
  (void)ws_size;

  (void)hipMemsetAsync(gcur, 0, NREG * 4, stream);

  const int nbin = (E + TILE - 1) / TILE;          // 782
  k_bin<<<nbin, 256, 0, stream>>>(src, dst, gcur, breg, E, npr);
  k_sort<<<nsubt, 256, 0, stream>>>(breg, gcur, dinv, rowinfo, csr, N, npr);
  k_linear<<<1563, 256, 0, stream>>>(x, W, dinv, hs, N);
  k_agg<<<(N + 3) / 4, 256, 0, stream>>>(hs, dinv, rowinfo, csr, b, out, N);
}

// Round 11
// 155.426 us; speedup vs baseline: 1.4557x; 1.4557x over previous
//
#include <hip/hip_runtime.h>

#define H 128
#define NREG 8
#define KE 8
#define TILE (256 * KE)    // k_bin: 2048 edges/block
#define B2T 4096           // k_bin2 tile
#define SCAP 3072          // per-sub-bucket capacity (avg 2048, +22 sigma)
#define RCAP 220160        // per-region capacity (avg 200000, +48 sigma)

typedef __attribute__((ext_vector_type(8))) short short8_t;   // 8 bf16
typedef __attribute__((ext_vector_type(4))) float float4_t;

__device__ __forceinline__ ushort f2bf(float f) {
  uint u = __float_as_uint(f);
  u += 0x7fff + ((u >> 16) & 1);          // RNE
  return (ushort)(u >> 16);
}
__device__ __forceinline__ float bflo(uint v) { return __uint_as_float(v << 16); }
__device__ __forceinline__ float bfhi(uint v) { return __uint_as_float(v & 0xffff0000u); }

// ---------- phase A: bin edges into 8 dst-regions, packed (src<<14 | d_local) ----------
// LDS-staged so global writes are 8 dense runs per block.
__global__ __launch_bounds__(256) void k_bin(const int* __restrict__ src, const int* __restrict__ dst,
                                             int* gcur, int* __restrict__ breg, int E, int npr) {
  __shared__ int cnt8[NREG], gbase8[NREG], lpre8[NREG + 1];
  __shared__ int staged[TILE];
  const int tid = threadIdx.x;
  if (tid < NREG) cnt8[tid] = 0;
  __syncthreads();
  const int base = blockIdx.x * TILE;
  int pk[KE], r[KE], off[KE];
  #pragma unroll
  for (int k = 0; k < KE; ++k) {
    const int e = base + k * 256 + tid;
    if (e < E) {
      const int s = src[e], d = dst[e];
      r[k] = (int)((unsigned)d / (unsigned)npr);
      pk[k] = (s << 14) | (d - r[k] * npr);
      off[k] = atomicAdd(&cnt8[r[k]], 1);
    } else r[k] = -1;
  }
  __syncthreads();
  if (tid == 0) {
    int acc = 0;
    #pragma unroll
    for (int j = 0; j < NREG; ++j) { lpre8[j] = acc; acc += cnt8[j]; }
    lpre8[NREG] = acc;
  }
  if (tid < NREG) gbase8[tid] = atomicAdd(&gcur[tid], cnt8[tid]);
  __syncthreads();
  #pragma unroll
  for (int k = 0; k < KE; ++k)
    if (r[k] >= 0) staged[lpre8[r[k]] + off[k]] = pk[k];
  __syncthreads();
  const int tot = lpre8[NREG];
  for (int i = tid; i < tot; i += 256) {
    int reg = 0;
    #pragma unroll
    for (int j = 1; j < NREG; ++j) reg += (i >= lpre8[j]);
    const int p = gbase8[reg] + (i - lpre8[reg]);
    if (p < RCAP) breg[reg * RCAP + p] = staged[i];
  }
}

// ---------- phase B: region bucket -> 128-node sub-buckets (dense run writes, NO deg) ----------
__global__ __launch_bounds__(256) void k_bin2(const int* __restrict__ breg, const int* __restrict__ gcur,
                                              int* cur2, int* __restrict__ bsub, int nsub) {
  __shared__ int cnt[128], lcur[128], lpre[128], gb[128];
  __shared__ int staged[B2T];
  const int tid = threadIdx.x;
  const int r = blockIdx.x & 7;
  const int t0 = (blockIdx.x >> 3) * B2T;
  const int total = min(gcur[r], RCAP);
  if (t0 >= total) return;
  const int cntT = min(B2T, total - t0);
  for (int i = tid; i < 128; i += 256) { cnt[i] = 0; lcur[i] = 0; }
  __syncthreads();
  const int* bp = breg + (size_t)r * RCAP + t0;
  for (int i = tid; i < cntT; i += 256) atomicAdd(&cnt[(bp[i] >> 7) & 127], 1);
  __syncthreads();
  if (tid < 128) lpre[tid] = cnt[tid];
  __syncthreads();
  for (int off = 1; off < 128; off <<= 1) {
    int v = 0;
    if (tid < 128 && tid >= off) v = lpre[tid - off];
    __syncthreads();
    if (tid < 128) lpre[tid] += v;
    __syncthreads();
  }
  if (tid < 128) {
    lpre[tid] -= cnt[tid];          // exclusive
    const int c = cnt[tid];
    gb[tid] = c ? atomicAdd(&cur2[r * nsub + tid], c) : 0;
  }
  __syncthreads();
  for (int i = tid; i < cntT; i += 256) {
    const int v = bp[i];
    const int sub = (v >> 7) & 127;
    const int pos = lpre[sub] + atomicAdd(&lcur[sub], 1);
    staged[pos] = (sub << 24) | ((v >> 14) << 7) | (v & 127);
  }
  __syncthreads();
  for (int i = tid; i < cntT; i += 256) {
    const int v = staged[i];
    const int sub = (int)((unsigned)v >> 24);
    const int pos = gb[sub] + (i - lpre[sub]);
    if (pos < SCAP) bsub[((size_t)(r * nsub + sub)) * SCAP + pos] = v & 0xFFFFFF;
  }
}

// ---------- phase C: per sub-bucket counting sort; emits dinv, rowinfo, dense csr ----------
// sid = r*nsub + sub used CONSISTENTLY for bsub/cur2/csr slots (round-10 bug fix).
__global__ __launch_bounds__(256) void k_fill3(const int* __restrict__ bsub, const int* __restrict__ cur2,
                                               float* __restrict__ dinv, uint4* __restrict__ rowinfo,
                                               int* __restrict__ csr, int N, int npr, int nsub) {
  __shared__ int cnt[128], pre[128], lcur[128];
  __shared__ int stage[SCAP], sorted[SCAP];
  const int tid = threadIdx.x;
  const int r = blockIdx.x & 7;
  const int sub = blockIdx.x >> 3;
  const int sid = r * nsub + sub;                 // bucket id (matches k_bin2 layout)
  const int gn0 = r * npr + sub * 128;
  int nodes = npr - sub * 128; if (nodes > 128) nodes = 128;
  if (N - gn0 < nodes) nodes = N - gn0;
  if (nodes <= 0) return;
  if (tid < 128) cnt[tid] = 0;
  __syncthreads();

  const int slotbase = sid * SCAP;
  const int cc = min(cur2[sid], SCAP);
  const int* bp = bsub + (size_t)slotbase;
  for (int i = tid; i < cc; i += 256) {
    const int v = bp[i];
    stage[i] = v;
    atomicAdd(&cnt[v & 127], 1);
  }
  __syncthreads();

  // exclusive scan of cnt[128]
  if (tid < 128) pre[tid] = cnt[tid];
  __syncthreads();
  for (int off = 1; off < 128; off <<= 1) {
    int v = 0;
    if (tid < 128 && tid >= off) v = pre[tid - off];
    __syncthreads();
    if (tid < 128) pre[tid] += v;
    __syncthreads();
  }
  if (tid < 128) pre[tid] -= cnt[tid];
  __syncthreads();

  // per-node outputs
  if (tid < nodes) {
    const int c = cnt[tid];
    const float dv = rsqrtf((float)(1 + c));
    dinv[gn0 + tid] = dv;
    rowinfo[gn0 + tid] = make_uint4((uint)(slotbase + pre[tid]), (uint)c, __float_as_uint(dv), 0u);
    lcur[tid] = pre[tid];
  }
  __syncthreads();

  // counting sort stage -> sorted (src values)
  for (int i = tid; i < cc; i += 256) {
    const int v = stage[i];
    const int p = atomicAdd(&lcur[v & 127], 1);
    sorted[p] = (int)((unsigned)v >> 7);
  }
  __syncthreads();
  for (int i = tid; i < cc; i += 256) csr[slotbase + i] = sorted[i];
}

// ---------- linear: hs = (x @ W^T) * dinv[row], bf16 ----------
__global__ __launch_bounds__(256) void k_linear(const float* __restrict__ x, const float* __restrict__ W,
                                                const float* __restrict__ dinv, ushort* __restrict__ hs, int N) {
  __shared__ float CT[32 * 128];
  const int tid  = threadIdx.x;
  const int lane = tid & 63;
  const int wid  = tid >> 6;
  const int rg   = wid >> 1;
  const int cg   = wid & 1;
  const int q    = lane >> 4;
  const int lm   = lane & 15;

  short8_t bfr[4][4];
  #pragma unroll
  for (int kk = 0; kk < 4; ++kk) {
    #pragma unroll
    for (int nf = 0; nf < 4; ++nf) {
      const float* wp = W + (cg * 64 + nf * 16 + lm) * 128 + kk * 32 + q * 8;
      float4_t w0 = *(const float4_t*)wp;
      float4_t w1 = *(const float4_t*)(wp + 4);
      union { short8_t s; ushort u[8]; } t;
      t.u[0] = f2bf(w0.x); t.u[1] = f2bf(w0.y); t.u[2] = f2bf(w0.z); t.u[3] = f2bf(w0.w);
      t.u[4] = f2bf(w1.x); t.u[5] = f2bf(w1.y); t.u[6] = f2bf(w1.z); t.u[7] = f2bf(w1.w);
      bfr[kk][nf] = t.s;
    }
  }

  const int ntiles = (N + 31) / 32;
  for (int tile = blockIdx.x; tile < ntiles; tile += gridDim.x) {
    const int n0 = tile * 32;
    const int arow = n0 + rg * 16 + lm;
    const int arow_c = (arow < N) ? arow : (N - 1);
    const float* xp = x + (long)arow_c * H + q * 8;
    short8_t afr[4];
    #pragma unroll
    for (int kk = 0; kk < 4; ++kk) {
      float4_t x0 = *(const float4_t*)(xp + kk * 32);
      float4_t x1 = *(const float4_t*)(xp + kk * 32 + 4);
      union { short8_t s; ushort u[8]; } t;
      t.u[0] = f2bf(x0.x); t.u[1] = f2bf(x0.y); t.u[2] = f2bf(x0.z); t.u[3] = f2bf(x0.w);
      t.u[4] = f2bf(x1.x); t.u[5] = f2bf(x1.y); t.u[6] = f2bf(x1.z); t.u[7] = f2bf(x1.w);
      afr[kk] = t.s;
    }

    float4_t acc[4];
    #pragma unroll
    for (int nf = 0; nf < 4; ++nf) acc[nf] = (float4_t){0.f, 0.f, 0.f, 0.f};
    #pragma unroll
    for (int kk = 0; kk < 4; ++kk) {
      #pragma unroll
      for (int nf = 0; nf < 4; ++nf)
        acc[nf] = __builtin_amdgcn_mfma_f32_16x16x32_bf16(afr[kk], bfr[kk][nf], acc[nf], 0, 0, 0);
    }

    #pragma unroll
    for (int nf = 0; nf < 4; ++nf) {
      #pragma unroll
      for (int rr = 0; rr < 4; ++rr)
        CT[(rg * 16 + q * 4 + rr) * 128 + cg * 64 + nf * 16 + lm] = acc[nf][rr];
    }
    __syncthreads();

    #pragma unroll
    for (int c = 0; c < 4; ++c) {
      const int flat = c * 1024 + tid * 4;
      const int row = flat >> 7;
      const int col = flat & 127;
      const int grow = n0 + row;
      if (grow < N) {
        float4_t v = *(const float4_t*)&CT[flat];
        const float dv = dinv[grow];
        uint2 pk;
        pk.x = (uint)f2bf(v.x * dv) | ((uint)f2bf(v.y * dv) << 16);
        pk.y = (uint)f2bf(v.z * dv) | ((uint)f2bf(v.w * dv) << 16);
        *(uint2*)(hs + (long)grow * H + col) = pk;
      }
    }
    __syncthreads();
  }
}

// ---------- aggregation: wave/node, XCD-pinned by dst region, 16-message rounds ----------
__global__ __launch_bounds__(256) void k_agg(const ushort* __restrict__ hs,
                                             const uint4* __restrict__ rowinfo, const int* __restrict__ csr,
                                             const float* __restrict__ bias, float* __restrict__ out,
                                             int N, int npr) {
  const int r = blockIdx.x & 7;
  const int ln = (blockIdx.x >> 3) * 4 + (threadIdx.x >> 6);
  if (ln >= npr) return;
  const int d = r * npr + ln;
  if (d >= N) return;
  const int l = threadIdx.x & 63;
  const int g = l >> 4, j = l & 15;
  const uint4* hp = (const uint4*)hs;          // 16 uint4 per 128-bf16 row

  float a0 = 0, a1 = 0, a2 = 0, a3 = 0, a4 = 0, a5 = 0, a6 = 0, a7 = 0;
  if (g == 0) {                                // self message (hs already * dinv[d])
    const uint4 q = hp[(size_t)d * 16 + j];
    a0 = bflo(q.x); a1 = bfhi(q.x); a2 = bflo(q.y); a3 = bfhi(q.y);
    a4 = bflo(q.z); a5 = bfhi(q.z); a6 = bflo(q.w); a7 = bfhi(q.w);
  }

  const uint4 info = rowinfo[d];
  int i = (int)info.x;
  int cnt = (int)info.y;
  const float dd = __uint_as_float(info.z);

  for (; cnt >= 16; cnt -= 16, i += 16) {
    const int sA = csr[i + g], sB = csr[i + 4 + g], sC = csr[i + 8 + g], sD = csr[i + 12 + g];
    const uint4 qA = hp[(size_t)sA * 16 + j];
    const uint4 qB = hp[(size_t)sB * 16 + j];
    const uint4 qC = hp[(size_t)sC * 16 + j];
    const uint4 qD = hp[(size_t)sD * 16 + j];
    a0 += bflo(qA.x) + bflo(qB.x) + bflo(qC.x) + bflo(qD.x);
    a1 += bfhi(qA.x) + bfhi(qB.x) + bfhi(qC.x) + bfhi(qD.x);
    a2 += bflo(qA.y) + bflo(qB.y) + bflo(qC.y) + bflo(qD.y);
    a3 += bfhi(qA.y) + bfhi(qB.y) + bfhi(qC.y) + bfhi(qD.y);
    a4 += bflo(qA.z) + bflo(qB.z) + bflo(qC.z) + bflo(qD.z);
    a5 += bfhi(qA.z) + bfhi(qB.z) + bfhi(qC.z) + bfhi(qD.z);
    a6 += bflo(qA.w) + bflo(qB.w) + bflo(qC.w) + bflo(qD.w);
    a7 += bfhi(qA.w) + bfhi(qB.w) + bfhi(qC.w) + bfhi(qD.w);
  }
  for (; cnt >= 4; cnt -= 4, i += 4) {
    const int s = csr[i + g];
    const uint4 q = hp[(size_t)s * 16 + j];
    a0 += bflo(q.x); a1 += bfhi(q.x); a2 += bflo(q.y); a3 += bfhi(q.y);
    a4 += bflo(q.z); a5 += bfhi(q.z); a6 += bflo(q.w); a7 += bfhi(q.w);
  }
  if (g < cnt) {
    const int s = csr[i + g];
    const uint4 q = hp[(size_t)s * 16 + j];
    a0 += bflo(q.x); a1 += bfhi(q.x); a2 += bflo(q.y); a3 += bfhi(q.y);
    a4 += bflo(q.z); a5 += bfhi(q.z); a6 += bflo(q.w); a7 += bfhi(q.w);
  }

  a0 += __shfl_xor(a0, 16); a1 += __shfl_xor(a1, 16);
  a2 += __shfl_xor(a2, 16); a3 += __shfl_xor(a3, 16);
  a4 += __shfl_xor(a4, 16); a5 += __shfl_xor(a5, 16);
  a6 += __shfl_xor(a6, 16); a7 += __shfl_xor(a7, 16);
  a0 += __shfl_xor(a0, 32); a1 += __shfl_xor(a1, 32);
  a2 += __shfl_xor(a2, 32); a3 += __shfl_xor(a3, 32);
  a4 += __shfl_xor(a4, 32); a5 += __shfl_xor(a5, 32);
  a6 += __shfl_xor(a6, 32); a7 += __shfl_xor(a7, 32);

  if (l < 16) {
    const float4_t b0 = *(const float4_t*)(bias + j * 8);
    const float4_t b1 = *(const float4_t*)(bias + j * 8 + 4);
    float4_t o0, o1;
    o0.x = a0 * dd + b0.x; o0.y = a1 * dd + b0.y; o0.z = a2 * dd + b0.z; o0.w = a3 * dd + b0.w;
    o1.x = a4 * dd + b1.x; o1.y = a5 * dd + b1.y; o1.z = a6 * dd + b1.z; o1.w = a7 * dd + b1.w;
    __builtin_nontemporal_store(o0, (float4_t*)(out + (size_t)d * H + j * 8));
    __builtin_nontemporal_store(o1, (float4_t*)(out + (size_t)d * H + j * 8 + 4));
  }
}

extern "C" void kernel_launch(void* const* d_in, const int* in_sizes, int n_in,
                              void* d_out, int out_size, void* d_ws, size_t ws_size,
                              hipStream_t stream) {
  const float* x = (const float*)d_in[0];
  const int*   edge = (const int*)d_in[1];
  const float* W = (const float*)d_in[2];
  const float* b = (const float*)d_in[3];
  float* out = (float*)d_out;

  const int N = in_sizes[0] / H;     // 100000
  const int E = in_sizes[1] / 2;     // 1600000
  const int* src = edge;
  const int* dst = edge + E;
  const int npr  = (N + NREG - 1) / NREG;           // 12500
  const int nsub = (npr + 127) / 128;               // 98
  const int nsubt = NREG * nsub;                    // 784

  // workspace layout (gcur + cur2 contiguous -> one memset)
  char* w = (char*)d_ws;
  ushort* hs     = (ushort*)w;  w += (size_t)N * H * 2;              // 25.6 MB
  float*  dinv   = (float*)w;   w += (size_t)N * 4;
  int*    gcur   = (int*)w;     w += (size_t)NREG * 4;
  int*    cur2   = (int*)w;     w += (size_t)nsubt * 4;
  uint4*  rowinfo= (uint4*)w;   w += (size_t)N * 16;                 // 1.6 MB
  int*    csr    = (int*)w;     w += (size_t)nsubt * SCAP * 4;       // 9.6 MB (fixed slots)
  int*    breg   = (int*)w;     w += (size_t)NREG * RCAP * 4;        // 7.0 MB
  int*    bsub   = (int*)w;     w += (size_t)nsubt * SCAP * 4;       // 9.6 MB
  (void)ws_size;

  (void)hipMemsetAsync(gcur, 0, (size_t)(NREG + nsubt) * 4, stream);

  const int nbin = (E + TILE - 1) / TILE;          // 782
  const int bpr2 = (RCAP + B2T - 1) / B2T;         // 54
  k_bin<<<nbin, 256, 0, stream>>>(src, dst, gcur, breg, E, npr);
  k_bin2<<<8 * bpr2, 256, 0, stream>>>(breg, gcur, cur2, bsub, nsub);
  k_fill3<<<nsubt, 256, 0, stream>>>(bsub, cur2, dinv, rowinfo, csr, N, npr, nsub);
  k_linear<<<1563, 256, 0, stream>>>(x, W, dinv, hs, N);
  k_agg<<<8 * ((npr + 3) / 4), 256, 0, stream>>>(hs, rowinfo, csr, b, out, N, npr);
}